// Round 1
// baseline (511.921 us; speedup 1.0000x reference)
//
#include <hip/hip_runtime.h>

#define NROWS 13107200          // 32*640*640
#define HW    409600            // 640*640
#define N4    (NROWS/4)
#define CBINS 8192              // top-13-bit histogram
#define FBINS 4096              // next-12-bit fine histogram
#define BLOCKS 1024
#define TPB    256

struct Ctl {
  double posLoss;     // sum over pos rows of se*w
  double sumW;        // sum over pos rows of w
  double sumAbove;    // exact sum of se in coarse bins > cutoff
  unsigned posCount;
  unsigned negCount;
  unsigned cutoffBin;
  unsigned kRemain;
  unsigned kSel;
  unsigned pad0, pad1, pad2;
};

__device__ inline float wredf(float v) {
  #pragma unroll
  for (int o = 32; o > 0; o >>= 1) v += __shfl_down(v, o, 64);
  return v;
}
__device__ inline unsigned wredu(unsigned v) {
  #pragma unroll
  for (int o = 32; o > 0; o >>= 1) v += (unsigned)__shfl_down((int)v, o, 64);
  return v;
}

// Pass 1: pos stats + coarse histogram (top 13 bits of float bits of se) over negatives.
// Optionally caches se (neg rows) / -1.0f (others) into `cache`.
__global__ __launch_bounds__(TPB)
void pass1(const float* __restrict__ pred, const float* __restrict__ vmk,
           const float* __restrict__ wgt, Ctl* __restrict__ ctl,
           unsigned* __restrict__ hist, float* __restrict__ cache)
{
  __shared__ unsigned lh[CBINS];
  for (int j = threadIdx.x; j < CBINS; j += TPB) lh[j] = 0;
  __syncthreads();

  float posLoss = 0.f, sumW = 0.f;
  unsigned posC = 0, negC = 0;
  const int stride = gridDim.x * TPB;
  for (int g = blockIdx.x * TPB + threadIdx.x; g < N4; g += stride) {
    const int i = g << 2;
    const int b = i / HW;          // group of 4 rows never crosses a batch (HW % 4 == 0)
    const int hw = i - b * HW;
    const size_t base = (size_t)b * (size_t)(2 * HW) + (size_t)hw;
    const float4 w4 = *(const float4*)(wgt + i);
    const float4 p0 = *(const float4*)(pred + base);
    const float4 p1 = *(const float4*)(pred + base + HW);
    const float4 t0 = *(const float4*)(vmk + base);
    const float4 t1 = *(const float4*)(vmk + base + HW);
    float se[4], wv[4];
    {
      float a, c;
      a = p0.x - t0.x; c = p1.x - t1.x; se[0] = a*a + c*c;
      a = p0.y - t0.y; c = p1.y - t1.y; se[1] = a*a + c*c;
      a = p0.z - t0.z; c = p1.z - t1.z; se[2] = a*a + c*c;
      a = p0.w - t0.w; c = p1.w - t1.w; se[3] = a*a + c*c;
    }
    wv[0] = w4.x; wv[1] = w4.y; wv[2] = w4.z; wv[3] = w4.w;
    float cv[4];
    #pragma unroll
    for (int c = 0; c < 4; ++c) {
      const float w = wv[c];
      const float s = se[c];
      if (w > 0.f)       { posC++; sumW += w; posLoss += s * w; cv[c] = -1.f; }
      else if (w == 0.f) { negC++; atomicAdd(&lh[__float_as_uint(s) >> 19], 1u); cv[c] = s; }
      else               { cv[c] = -1.f; }   // mimic ref: w<0 is neither pos nor neg
    }
    if (cache) *(float4*)(cache + i) = make_float4(cv[0], cv[1], cv[2], cv[3]);
  }

  posLoss = wredf(posLoss); sumW = wredf(sumW);
  posC = wredu(posC); negC = wredu(negC);
  if ((threadIdx.x & 63) == 0) {
    atomicAdd(&ctl->posLoss, (double)posLoss);
    atomicAdd(&ctl->sumW, (double)sumW);
    atomicAdd(&ctl->posCount, posC);
    atomicAdd(&ctl->negCount, negC);
  }
  __syncthreads();
  for (int j = threadIdx.x; j < CBINS; j += TPB) {
    const unsigned c = lh[j];
    if (c) atomicAdd(&hist[j], c);   // zero-skip: ~1k populated bins
  }
}

// Find cutoff coarse bin: largest b with count(bins > b) < k <= count(bins >= b)
__global__ __launch_bounds__(256)
void scan_coarse(Ctl* __restrict__ ctl, const unsigned* __restrict__ hist)
{
  __shared__ unsigned chunk[256];
  const int t = threadIdx.x;
  unsigned s = 0;
  #pragma unroll
  for (int j = 0; j < CBINS / 256; ++j) s += hist[t * (CBINS / 256) + j];
  chunk[t] = s;
  __syncthreads();
  if (t == 0) {
    const unsigned posC = ctl->posCount;
    const unsigned negC = ctl->negCount;
    const unsigned long long k3 = 3ull * (unsigned long long)posC;
    const unsigned k = (k3 < (unsigned long long)negC) ? (unsigned)k3 : negC;
    ctl->kSel = k;
    if (k == 0) { ctl->cutoffBin = 0xFFFFFFFFu; ctl->kRemain = 0; return; }
    unsigned A = 0;
    int cc = 255;
    for (; cc >= 0; --cc) {
      if (A + chunk[cc] >= k) break;
      A += chunk[cc];
    }
    int bin = cc * (CBINS / 256) + (CBINS / 256 - 1);
    for (;; --bin) {
      const unsigned c = hist[bin];
      if (A + c >= k) break;
      A += c;
    }
    ctl->cutoffBin = (unsigned)bin;
    ctl->kRemain = k - A;       // 1..hist[bin]
  }
}

__device__ inline void procNeg(float s, unsigned cut,
                               unsigned* lc, float* ls, float& above)
{
  const unsigned bits = __float_as_uint(s);
  const unsigned bin = bits >> 19;
  if (bin > cut) above += s;
  else if (bin == cut) {
    const unsigned f = (bits >> 7) & (FBINS - 1);
    atomicAdd(&lc[f], 1u);
    atomicAdd(&ls[f], s);
  }
}

// Pass 2: exact sum above cutoff bin; fine histogram (counts + sums) within cutoff bin.
__global__ __launch_bounds__(TPB)
void pass2(const float* __restrict__ pred, const float* __restrict__ vmk,
           const float* __restrict__ wgt, Ctl* __restrict__ ctl,
           unsigned* __restrict__ fcnt, float* __restrict__ fsum,
           const float* __restrict__ cache)
{
  __shared__ unsigned lc[FBINS];
  __shared__ float ls[FBINS];
  for (int j = threadIdx.x; j < FBINS; j += TPB) { lc[j] = 0; ls[j] = 0.f; }
  __syncthreads();

  const unsigned cut = ctl->cutoffBin;
  float above = 0.f;
  const int stride = gridDim.x * TPB;
  if (cache) {
    for (int g = blockIdx.x * TPB + threadIdx.x; g < N4; g += stride) {
      const int i = g << 2;
      const float4 s4 = *(const float4*)(cache + i);
      const float sv[4] = { s4.x, s4.y, s4.z, s4.w };
      #pragma unroll
      for (int c = 0; c < 4; ++c)
        if (sv[c] >= 0.f) procNeg(sv[c], cut, lc, ls, above);
    }
  } else {
    for (int g = blockIdx.x * TPB + threadIdx.x; g < N4; g += stride) {
      const int i = g << 2;
      const int b = i / HW;
      const int hw = i - b * HW;
      const size_t base = (size_t)b * (size_t)(2 * HW) + (size_t)hw;
      const float4 w4 = *(const float4*)(wgt + i);
      const float4 p0 = *(const float4*)(pred + base);
      const float4 p1 = *(const float4*)(pred + base + HW);
      const float4 t0 = *(const float4*)(vmk + base);
      const float4 t1 = *(const float4*)(vmk + base + HW);
      float se[4], wv[4];
      {
        float a, c;
        a = p0.x - t0.x; c = p1.x - t1.x; se[0] = a*a + c*c;
        a = p0.y - t0.y; c = p1.y - t1.y; se[1] = a*a + c*c;
        a = p0.z - t0.z; c = p1.z - t1.z; se[2] = a*a + c*c;
        a = p0.w - t0.w; c = p1.w - t1.w; se[3] = a*a + c*c;
      }
      wv[0] = w4.x; wv[1] = w4.y; wv[2] = w4.z; wv[3] = w4.w;
      #pragma unroll
      for (int c = 0; c < 4; ++c)
        if (wv[c] == 0.f) procNeg(se[c], cut, lc, ls, above);
    }
  }

  above = wredf(above);
  if ((threadIdx.x & 63) == 0) atomicAdd(&ctl->sumAbove, (double)above);
  __syncthreads();
  for (int j = threadIdx.x; j < FBINS; j += TPB) {
    const unsigned c = lc[j];
    if (c) { atomicAdd(&fcnt[j], c); atomicAdd(&fsum[j], ls[j]); }
  }
}

// Fine scan + final loss.
__global__ __launch_bounds__(256)
void scan_finish(Ctl* __restrict__ ctl, const unsigned* __restrict__ fcnt,
                 const float* __restrict__ fsum, float* __restrict__ out)
{
  __shared__ unsigned chunk[256];
  __shared__ float chunkS[256];
  const int t = threadIdx.x;
  unsigned s = 0; float ss = 0.f;
  #pragma unroll
  for (int j = 0; j < FBINS / 256; ++j) {
    s  += fcnt[t * (FBINS / 256) + j];
    ss += fsum[t * (FBINS / 256) + j];
  }
  chunk[t] = s; chunkS[t] = ss;
  __syncthreads();
  if (t == 0) {
    double sel = 0.0;
    const unsigned kRem = ctl->kRemain;
    if (kRem > 0) {
      unsigned A = 0; double S = 0.0;
      int cc = 255;
      for (; cc >= 0; --cc) {
        if (A + chunk[cc] >= kRem) break;
        A += chunk[cc]; S += (double)chunkS[cc];
      }
      int bin = cc * (FBINS / 256) + (FBINS / 256 - 1);
      for (;; --bin) {
        const unsigned c = fcnt[bin];
        if (A + c >= kRem) {
          const unsigned need = kRem - A;
          // crossing sub-bin: elements within 2^-16 relative width -> avg is (near-)exact
          sel = S + (double)fsum[bin] * ((double)need / (double)c);
          break;
        }
        A += c; S += (double)fsum[bin];
      }
    }
    const double num = ctl->posLoss + ctl->sumAbove + sel;
    const double den = 2.0 * ctl->sumW + 2.0 * (double)ctl->kSel;
    out[0] = (float)(num / den / 32.0);
  }
}

extern "C" void kernel_launch(void* const* d_in, const int* in_sizes, int n_in,
                              void* d_out, int out_size, void* d_ws, size_t ws_size,
                              hipStream_t stream)
{
  const float* pred = (const float*)d_in[0];
  const float* vmk  = (const float*)d_in[1];
  const float* wgt  = (const float*)d_in[2];
  char* ws = (char*)d_ws;
  Ctl* ctl       = (Ctl*)ws;
  unsigned* hist = (unsigned*)(ws + 64);
  unsigned* fcnt = (unsigned*)(ws + 64 + CBINS * 4);
  float* fsum    = (float*)(ws + 64 + CBINS * 4 + FBINS * 4);
  const size_t head = 64 + CBINS * 4 + FBINS * 4 + FBINS * 4;   // 65600 B
  const size_t cacheOff = 65664;                                 // 16B-aligned
  float* cache = (ws_size >= cacheOff + (size_t)NROWS * 4)
                   ? (float*)(ws + cacheOff) : nullptr;

  hipMemsetAsync(d_ws, 0, head, stream);  // ws is re-poisoned 0xAA before every call
  pass1<<<BLOCKS, TPB, 0, stream>>>(pred, vmk, wgt, ctl, hist, cache);
  scan_coarse<<<1, 256, 0, stream>>>(ctl, hist);
  pass2<<<BLOCKS, TPB, 0, stream>>>(pred, vmk, wgt, ctl, fcnt, fsum, cache);
  scan_finish<<<1, 256, 0, stream>>>(ctl, fcnt, fsum, (float*)d_out);
}